// Round 8
// baseline (6409.699 us; speedup 1.0000x reference)
//
#include <hip/hip_runtime.h>
#include <hip/hip_fp16.h>

#define NN 100000
#define NE 1600000
#define HD 128
#define HD2 256

typedef unsigned int u32;
typedef unsigned short u16;
typedef _Float16 half8 __attribute__((ext_vector_type(8)));
typedef float floatx4 __attribute__((ext_vector_type(4)));

static inline int cdiv(int a, int b){ return (a + b - 1) / b; }

// ---- split-fp16 packing: x ~= h + l * 2^-12, l pre-scaled by 4096 ----
__device__ __forceinline__ u32 split_pack(float v){
  __half h;
  if(fabsf(v) < 6.103515625e-05f) h = __ushort_as_half((u16)0);
  else h = __float2half_rn(v);
  float hf = __half2float(h);
  __half l = __float2half_rn((v - hf) * 4096.0f);
  return (u32)__half_as_ushort(h) | ((u32)__half_as_ushort(l) << 16);
}

// ---------------- utility kernels ----------------
__global__ void k_zero_int(int* __restrict__ p, int n){
  int i = blockIdx.x * 256 + threadIdx.x;
  if(i < n) p[i] = 0;
}

__global__ void k_zero_f(float* __restrict__ p, int n){
  int i = blockIdx.x * 256 + threadIdx.x;
  if(i < n) p[i] = 0.f;
}

// ---------------- CSR build (per-adjacency, packed col+val) ----------------
__global__ void k_hist(const int* __restrict__ rows, int* __restrict__ cnt){
  int e = blockIdx.x * 256 + threadIdx.x;
  if(e < NE) atomicAdd(&cnt[rows[e]], 1);
}

__global__ void k_scan1(const int* __restrict__ cnt, int* __restrict__ part,
                        int* __restrict__ sums, int n){
  __shared__ int sh[256];
  int tid = threadIdx.x;
  int base = blockIdx.x * 1024 + tid * 4;
  int v0 = (base + 0 < n) ? cnt[base + 0] : 0;
  int v1 = (base + 1 < n) ? cnt[base + 1] : 0;
  int v2 = (base + 2 < n) ? cnt[base + 2] : 0;
  int v3 = (base + 3 < n) ? cnt[base + 3] : 0;
  int s = v0 + v1 + v2 + v3;
  sh[tid] = s;
  __syncthreads();
  for(int d = 1; d < 256; d <<= 1){
    int t = (tid >= d) ? sh[tid - d] : 0;
    __syncthreads();
    sh[tid] += t;
    __syncthreads();
  }
  int excl = sh[tid] - s;
  if(tid == 255) sums[blockIdx.x] = sh[255];
  if(base + 0 < n) part[base + 0] = excl;
  if(base + 1 < n) part[base + 1] = excl + v0;
  if(base + 2 < n) part[base + 2] = excl + v0 + v1;
  if(base + 3 < n) part[base + 3] = excl + v0 + v1 + v2;
}

__global__ void k_scan2(int* __restrict__ sums, int nb){
  __shared__ int sh[128];
  int tid = threadIdx.x;
  int v = (tid < nb) ? sums[tid] : 0;
  sh[tid] = v;
  __syncthreads();
  for(int d = 1; d < 128; d <<= 1){
    int t = (tid >= d) ? sh[tid - d] : 0;
    __syncthreads();
    sh[tid] += t;
    __syncthreads();
  }
  if(tid < nb) sums[tid] = sh[tid] - v;
}

__global__ void k_scan3(int* __restrict__ rowptr, int* __restrict__ cursor,
                        const int* __restrict__ sums, int n){
  int tid = threadIdx.x;
  int off = sums[blockIdx.x];
  int base = blockIdx.x * 1024 + tid * 4;
  #pragma unroll
  for(int j = 0; j < 4; j++){
    int idx = base + j;
    if(idx < n){ int r = rowptr[idx] + off; rowptr[idx] = r; cursor[idx] = r; }
  }
  if(blockIdx.x == 0 && tid == 0) rowptr[n] = NE;
}

__global__ void k_scatter(const int* __restrict__ rows, const int* __restrict__ cols,
                          const float* __restrict__ vals, int* __restrict__ cursor,
                          uint2* __restrict__ ecv){
  int e = blockIdx.x * 256 + threadIdx.x;
  if(e < NE){
    int r = rows[e];
    int pp = atomicAdd(&cursor[r], 1);
    ecv[pp] = make_uint2((u32)cols[e], __float_as_uint(vals[e]));
  }
}

// weight pre-split: W is [K][N] row-major fp32; out is packed [N][K] (transposed)
__global__ void k_splitw(const float* __restrict__ W, u32* __restrict__ out,
                         int K, int N, int total){
  int idx = blockIdx.x * 256 + threadIdx.x;
  if(idx < total){
    int n = idx / K, k = idx - n * K;
    out[idx] = split_pack(W[(size_t)k * N + n]);
  }
}

// ---------------- wave-level SpMM body (packed ecv edges) ----------------
__device__ __forceinline__ void spmm_node(int node, int lane,
                                          const int* __restrict__ rowptr,
                                          const uint2* __restrict__ ecv,
                                          const float* __restrict__ X,
                                          u32* __restrict__ outpk, int norm){
  int s = rowptr[node], e = rowptr[node + 1];
  float ax = 0.f, ay = 0.f, bx = 0.f, by = 0.f;
  int i = s;
  for(; i + 15 < e; i += 16){
    uint2 ee[16]; float2 xx[16];
    #pragma unroll
    for(int j = 0; j < 16; j++) ee[j] = ecv[i + j];
    #pragma unroll
    for(int j = 0; j < 16; j++) xx[j] = *(const float2*)(X + (size_t)ee[j].x * HD + lane * 2);
    #pragma unroll
    for(int j = 0; j < 16; j += 4){
      ax += __uint_as_float(ee[j].y)   * xx[j].x   + __uint_as_float(ee[j+1].y) * xx[j+1].x;
      ay += __uint_as_float(ee[j].y)   * xx[j].y   + __uint_as_float(ee[j+1].y) * xx[j+1].y;
      bx += __uint_as_float(ee[j+2].y) * xx[j+2].x + __uint_as_float(ee[j+3].y) * xx[j+3].x;
      by += __uint_as_float(ee[j+2].y) * xx[j+2].y + __uint_as_float(ee[j+3].y) * xx[j+3].y;
    }
  }
  for(; i + 3 < e; i += 4){
    uint2 e0 = ecv[i], e1 = ecv[i+1], e2 = ecv[i+2], e3 = ecv[i+3];
    float2 x0 = *(const float2*)(X + (size_t)e0.x * HD + lane * 2);
    float2 x1 = *(const float2*)(X + (size_t)e1.x * HD + lane * 2);
    float2 x2 = *(const float2*)(X + (size_t)e2.x * HD + lane * 2);
    float2 x3 = *(const float2*)(X + (size_t)e3.x * HD + lane * 2);
    ax += __uint_as_float(e0.y) * x0.x + __uint_as_float(e1.y) * x1.x;
    ay += __uint_as_float(e0.y) * x0.y + __uint_as_float(e1.y) * x1.y;
    bx += __uint_as_float(e2.y) * x2.x + __uint_as_float(e3.y) * x3.x;
    by += __uint_as_float(e2.y) * x2.y + __uint_as_float(e3.y) * x3.y;
  }
  for(; i < e; i++){
    uint2 e0 = ecv[i];
    float2 xv = *(const float2*)(X + (size_t)e0.x * HD + lane * 2);
    ax += __uint_as_float(e0.y) * xv.x;
    ay += __uint_as_float(e0.y) * xv.y;
  }
  ax += bx; ay += by;
  ax = fmaxf(ax, 0.f);
  ay = fmaxf(ay, 0.f);
  if(norm){
    float ss = ax * ax + ay * ay;
    #pragma unroll
    for(int o = 32; o >= 1; o >>= 1) ss += __shfl_xor(ss, o, 64);
    float scale = 1.f / fmaxf(sqrtf(ss), 1e-12f);
    ax *= scale; ay *= scale;
  }
  *(uint2*)(outpk + (size_t)node * HD + lane * 2) = make_uint2(split_pack(ax), split_pack(ay));
}

// ---------------- standalone SpMM: one wave per node ----------------
template<bool NORM>
__global__ void k_spmm(const int* __restrict__ rowptr, const uint2* __restrict__ ecv,
                       const float* __restrict__ X, u32* __restrict__ outpk){
  int node = (blockIdx.x << 2) + (threadIdx.x >> 6);
  int lane = threadIdx.x & 63;
  if(node >= NN) return;
  spmm_node(node, lane, rowptr, ecv, X, outpk, NORM ? 1 : 0);
}

// ---------------- split-fp16 MFMA GEMM (round-6-proven) ----------------
// A: packed [M][K]; Bt: packed [N][K] (pre-transposed).
// MODE 0: Yout = A@B (fp32). MODE 1: Hout = pack(relu(A@B+bias)).
// MODE 2: score[m] += sum_n relu(A@B+bias)[m][n]*m3[n].
template<int MODE>
__launch_bounds__(256, 2)
__global__ void k_mfma_gemm(const u32* __restrict__ Apk, const u32* __restrict__ Btpk,
                            const float* __restrict__ bias, float* __restrict__ Yout,
                            u32* __restrict__ Hout, const float* __restrict__ m3,
                            float* __restrict__ score, int M, int K, int N){
  __shared__ u16 As_h[128 * 40], As_l[128 * 40];
  __shared__ u16 Bs_h[128 * 40], Bs_l[128 * 40];
  const int tid = threadIdx.x;
  const int lane = tid & 63, wid = tid >> 6;
  const int lm = lane & 15, lg = lane >> 4;
  const int mq = (wid & 1) * 64, nq = (wid >> 1) * 64;
  const int m0 = blockIdx.x * 128, n0 = blockIdx.y * 128;

  floatx4 accA[4][4], accB[4][4];
  #pragma unroll
  for(int i = 0; i < 4; i++)
    #pragma unroll
    for(int j = 0; j < 4; j++){
      accA[i][j] = (floatx4){0.f, 0.f, 0.f, 0.f};
      accB[i][j] = (floatx4){0.f, 0.f, 0.f, 0.f};
    }

  for(int k0 = 0; k0 < K; k0 += 32){
    uint4 av[4], bv[4];
    #pragma unroll
    for(int j = 0; j < 4; j++){
      int li = tid + j * 256;
      int row = li >> 3, kc = (li & 7) * 4;
      int ar = m0 + row; if(ar >= M) ar = M - 1;
      av[j] = *(const uint4*)(Apk + (size_t)ar * K + k0 + kc);
      bv[j] = *(const uint4*)(Btpk + (size_t)(n0 + row) * K + k0 + kc);
    }
    __syncthreads();
    #pragma unroll
    for(int j = 0; j < 4; j++){
      int li = tid + j * 256;
      int row = li >> 3, kc = (li & 7) * 4;
      int base = row * 40 + kc;
      ushort4 h, l;
      h.x = (u16)(av[j].x & 0xffff); l.x = (u16)(av[j].x >> 16);
      h.y = (u16)(av[j].y & 0xffff); l.y = (u16)(av[j].y >> 16);
      h.z = (u16)(av[j].z & 0xffff); l.z = (u16)(av[j].z >> 16);
      h.w = (u16)(av[j].w & 0xffff); l.w = (u16)(av[j].w >> 16);
      *(ushort4*)&As_h[base] = h;
      *(ushort4*)&As_l[base] = l;
      h.x = (u16)(bv[j].x & 0xffff); l.x = (u16)(bv[j].x >> 16);
      h.y = (u16)(bv[j].y & 0xffff); l.y = (u16)(bv[j].y >> 16);
      h.z = (u16)(bv[j].z & 0xffff); l.z = (u16)(bv[j].z >> 16);
      h.w = (u16)(bv[j].w & 0xffff); l.w = (u16)(bv[j].w >> 16);
      *(ushort4*)&Bs_h[base] = h;
      *(ushort4*)&Bs_l[base] = l;
    }
    __syncthreads();

    half8 fa_h[4], fa_l[4], fb_h[4], fb_l[4];
    #pragma unroll
    for(int s = 0; s < 4; s++){
      int ra = (mq + s * 16 + lm) * 40 + lg * 8;
      fa_h[s] = *(const half8*)&As_h[ra];
      fa_l[s] = *(const half8*)&As_l[ra];
      int rb = (nq + s * 16 + lm) * 40 + lg * 8;
      fb_h[s] = *(const half8*)&Bs_h[rb];
      fb_l[s] = *(const half8*)&Bs_l[rb];
    }
    #pragma unroll
    for(int i = 0; i < 4; i++)
      #pragma unroll
      for(int j = 0; j < 4; j++){
        accA[i][j] = __builtin_amdgcn_mfma_f32_16x16x32_f16(fa_h[i], fb_h[j], accA[i][j], 0, 0, 0);
        accB[i][j] = __builtin_amdgcn_mfma_f32_16x16x32_f16(fa_h[i], fb_l[j], accB[i][j], 0, 0, 0);
        accB[i][j] = __builtin_amdgcn_mfma_f32_16x16x32_f16(fa_l[i], fb_h[j], accB[i][j], 0, 0, 0);
      }
  }

  const float inv4096 = 1.f / 4096.f;
  if(MODE == 0){
    #pragma unroll
    for(int i = 0; i < 4; i++)
      #pragma unroll
      for(int r = 0; r < 4; r++){
        int m = m0 + mq + i * 16 + lg * 4 + r;
        if(m < M){
          #pragma unroll
          for(int j = 0; j < 4; j++){
            int c = n0 + nq + j * 16 + lm;
            Yout[(size_t)m * N + c] = accA[i][j][r] + accB[i][j][r] * inv4096;
          }
        }
      }
  } else if(MODE == 1){
    #pragma unroll
    for(int i = 0; i < 4; i++)
      #pragma unroll
      for(int r = 0; r < 4; r++){
        int m = m0 + mq + i * 16 + lg * 4 + r;
        if(m < M){
          #pragma unroll
          for(int j = 0; j < 4; j++){
            int c = n0 + nq + j * 16 + lm;
            float v = fmaxf(accA[i][j][r] + accB[i][j][r] * inv4096 + bias[c], 0.f);
            Hout[(size_t)m * N + c] = split_pack(v);
          }
        }
      }
  } else {
    #pragma unroll
    for(int i = 0; i < 4; i++)
      #pragma unroll
      for(int r = 0; r < 4; r++){
        float s = 0.f;
        #pragma unroll
        for(int j = 0; j < 4; j++){
          int c = n0 + nq + j * 16 + lm;
          float v = fmaxf(accA[i][j][r] + accB[i][j][r] * inv4096 + bias[c], 0.f);
          s = fmaf(v, m3[c], s);
        }
        s += __shfl_xor(s, 1, 64);
        s += __shfl_xor(s, 2, 64);
        s += __shfl_xor(s, 4, 64);
        s += __shfl_xor(s, 8, 64);
        int m = m0 + mq + i * 16 + lg * 4 + r;
        if(lm == 0 && m < M) atomicAdd(&score[m], s);
      }
  }
}

// ---------------- fused persistent kernel: mode2 GEMM tiles + SpMM nodes ----------------
// Even blocks drain the GEMM tile queue first, odd blocks the SpMM queue first;
// both then help the other queue. Overlaps MFMA pipe with gather memory traffic.
__launch_bounds__(256, 2)
__global__ void k_fused(const u32* __restrict__ Apk, const u32* __restrict__ Btpk,
                        const float* __restrict__ bias, const float* __restrict__ m3,
                        float* __restrict__ score, int M, int Ngi,
                        const int* __restrict__ rowptr, const uint2* __restrict__ ecv,
                        const float* __restrict__ X, u32* __restrict__ outpk,
                        int norm, int* __restrict__ qa, int* __restrict__ qb){
  __shared__ u16 As_h[128 * 40], As_l[128 * 40];
  __shared__ u16 Bs_h[128 * 40], Bs_l[128 * 40];
  __shared__ int s_item;
  const int tid = threadIdx.x;
  const int lane = tid & 63, wid = tid >> 6;
  const int lm = lane & 15, lg = lane >> 4;
  const int mq = (wid & 1) * 64, nq = (wid >> 1) * 64;
  const int K = HD2;
  const float inv4096 = 1.f / 4096.f;

  auto do_gemm = [&](int g){
    int m0 = (g >> 1) * 128, n0 = (g & 1) * 128;
    floatx4 accA[4][4], accB[4][4];
    #pragma unroll
    for(int i = 0; i < 4; i++)
      #pragma unroll
      for(int j = 0; j < 4; j++){
        accA[i][j] = (floatx4){0.f, 0.f, 0.f, 0.f};
        accB[i][j] = (floatx4){0.f, 0.f, 0.f, 0.f};
      }
    for(int k0 = 0; k0 < K; k0 += 32){
      uint4 av[4], bv[4];
      #pragma unroll
      for(int j = 0; j < 4; j++){
        int li = tid + j * 256;
        int row = li >> 3, kc = (li & 7) * 4;
        int ar = m0 + row; if(ar >= M) ar = M - 1;
        av[j] = *(const uint4*)(Apk + (size_t)ar * K + k0 + kc);
        bv[j] = *(const uint4*)(Btpk + (size_t)(n0 + row) * K + k0 + kc);
      }
      __syncthreads();
      #pragma unroll
      for(int j = 0; j < 4; j++){
        int li = tid + j * 256;
        int row = li >> 3, kc = (li & 7) * 4;
        int base = row * 40 + kc;
        ushort4 h, l;
        h.x = (u16)(av[j].x & 0xffff); l.x = (u16)(av[j].x >> 16);
        h.y = (u16)(av[j].y & 0xffff); l.y = (u16)(av[j].y >> 16);
        h.z = (u16)(av[j].z & 0xffff); l.z = (u16)(av[j].z >> 16);
        h.w = (u16)(av[j].w & 0xffff); l.w = (u16)(av[j].w >> 16);
        *(ushort4*)&As_h[base] = h;
        *(ushort4*)&As_l[base] = l;
        h.x = (u16)(bv[j].x & 0xffff); l.x = (u16)(bv[j].x >> 16);
        h.y = (u16)(bv[j].y & 0xffff); l.y = (u16)(bv[j].y >> 16);
        h.z = (u16)(bv[j].z & 0xffff); l.z = (u16)(bv[j].z >> 16);
        h.w = (u16)(bv[j].w & 0xffff); l.w = (u16)(bv[j].w >> 16);
        *(ushort4*)&Bs_h[base] = h;
        *(ushort4*)&Bs_l[base] = l;
      }
      __syncthreads();
      half8 fa_h[4], fa_l[4], fb_h[4], fb_l[4];
      #pragma unroll
      for(int s = 0; s < 4; s++){
        int ra = (mq + s * 16 + lm) * 40 + lg * 8;
        fa_h[s] = *(const half8*)&As_h[ra];
        fa_l[s] = *(const half8*)&As_l[ra];
        int rb = (nq + s * 16 + lm) * 40 + lg * 8;
        fb_h[s] = *(const half8*)&Bs_h[rb];
        fb_l[s] = *(const half8*)&Bs_l[rb];
      }
      #pragma unroll
      for(int i = 0; i < 4; i++)
        #pragma unroll
        for(int j = 0; j < 4; j++){
          accA[i][j] = __builtin_amdgcn_mfma_f32_16x16x32_f16(fa_h[i], fb_h[j], accA[i][j], 0, 0, 0);
          accB[i][j] = __builtin_amdgcn_mfma_f32_16x16x32_f16(fa_h[i], fb_l[j], accB[i][j], 0, 0, 0);
          accB[i][j] = __builtin_amdgcn_mfma_f32_16x16x32_f16(fa_l[i], fb_h[j], accB[i][j], 0, 0, 0);
        }
    }
    #pragma unroll
    for(int i = 0; i < 4; i++)
      #pragma unroll
      for(int r = 0; r < 4; r++){
        float s = 0.f;
        #pragma unroll
        for(int j = 0; j < 4; j++){
          int c = n0 + nq + j * 16 + lm;
          float v = fmaxf(accA[i][j][r] + accB[i][j][r] * inv4096 + bias[c], 0.f);
          s = fmaf(v, m3[c], s);
        }
        s += __shfl_xor(s, 1, 64);
        s += __shfl_xor(s, 2, 64);
        s += __shfl_xor(s, 4, 64);
        s += __shfl_xor(s, 8, 64);
        int m = m0 + mq + i * 16 + lg * 4 + r;
        if(lm == 0 && m < M) atomicAdd(&score[m], s);
      }
  };

  auto gemm_loop = [&](){
    for(;;){
      __syncthreads();
      if(tid == 0) s_item = atomicAdd(qa, 1);
      __syncthreads();
      int g = s_item;
      if(g >= Ngi) break;
      do_gemm(g);
    }
  };
  auto spmm_loop = [&](){
    for(;;){
      int s;
      if(lane == 0) s = atomicAdd(qb, 16);
      s = __shfl(s, 0, 64);
      if(s >= NN) break;
      int e = s + 16; if(e > NN) e = NN;
      for(int n = s; n < e; n++)
        spmm_node(n, lane, rowptr, ecv, X, outpk, norm);
    }
  };

  if((blockIdx.x & 1) == 0){ gemm_loop(); spmm_loop(); }
  else                     { spmm_loop(); __syncthreads(); gemm_loop(); }
}

__global__ void k_final(const float* __restrict__ sc, const float* __restrict__ b3,
                        float* __restrict__ out){
  int i = blockIdx.x * 256 + threadIdx.x;
  if(i < NN){
    float b = 9.f * b3[0];
    out[i] = (sc[i] + b) * (sc[NN + i] + b);
  }
}

// ---------------- launcher ----------------
extern "C" void kernel_launch(void* const* d_in, const int* in_sizes, int n_in,
                              void* d_out, int out_size, void* d_ws, size_t ws_size,
                              hipStream_t stream){
  const int*   a1r = (const int*)d_in[0];
  const int*   a1c = (const int*)d_in[1];
  const float* a1v = (const float*)d_in[2];
  const int*   a2r = (const int*)d_in[3];
  const int*   a2c = (const int*)d_in[4];
  const float* a2v = (const float*)d_in[5];
  const float* w1  = (const float*)d_in[6];
  const float* w[8];
  for(int i = 0; i < 8; i++) w[i] = (const float*)d_in[7 + i];
  const float* m1 = (const float*)d_in[15];
  const float* b1 = (const float*)d_in[16];
  const float* m2 = (const float*)d_in[17];
  const float* b2 = (const float*)d_in[18];
  const float* m3 = (const float*)d_in[19];
  const float* b3 = (const float*)d_in[20];
  float* out = (float*)d_out;

  char* base = (char*)d_ws;
  size_t off = 0;
  auto alloc = [&](size_t bytes) -> char* {
    char* r = base + off;
    off += (bytes + 255) & ~(size_t)255;
    return r;
  };
  // fixed small buffers (single shared CSR, rebuilt per branch)
  int*   cptr  = (int*)  alloc((size_t)(NN + 1) * 4);
  uint2* ecv   = (uint2*)alloc((size_t)NE * 8);
  int*   cursor= (int*)  alloc((size_t)NN * 4);
  int*   sums  = (int*)  alloc(512);
  float* sc    = (float*)alloc((size_t)2 * NN * 4);
  int*   qcnt  = (int*)  alloc(64 * 4);
  u32*   wtpk[8];
  for(int i = 0; i < 8; i++) wtpk[i] = (u32*)alloc((size_t)HD * HD * 4);
  u32*   m1tpk = (u32*)alloc((size_t)HD2 * HD * 4);
  u32*   m2tpk = (u32*)alloc((size_t)HD2 * HD2 * 4);
  u32*   xpk   = (u32*)alloc((size_t)NN * HD * 4);
  u32*   h1pk  = (u32*)alloc((size_t)NN * HD2 * 4);
  // fused tier needs a dedicated y (fp32 [NN][128]); else y aliases h1pk (r6 schedule)
  size_t need_fused = off + (((size_t)NN * HD * 4 + 255) & ~(size_t)255);
  bool fused_tier = (ws_size >= need_fused);
  float* y = fused_tier ? (float*)alloc((size_t)NN * HD * 4) : (float*)h1pk;

  const int SCAN_BLOCKS = cdiv(NN, 1024);
  auto build_csr = [&](const int* rows, const int* cols, const float* vals){
    hipLaunchKernelGGL(k_zero_int, dim3(cdiv(NN, 256)), dim3(256), 0, stream, cursor, NN);
    hipLaunchKernelGGL(k_hist,     dim3(cdiv(NE, 256)), dim3(256), 0, stream, rows, cursor);
    hipLaunchKernelGGL(k_scan1,    dim3(SCAN_BLOCKS),   dim3(256), 0, stream, cursor, cptr, sums, NN);
    hipLaunchKernelGGL(k_scan2,    dim3(1),             dim3(128), 0, stream, sums, SCAN_BLOCKS);
    hipLaunchKernelGGL(k_scan3,    dim3(SCAN_BLOCKS),   dim3(256), 0, stream, cptr, cursor, sums, NN);
    hipLaunchKernelGGL(k_scatter,  dim3(cdiv(NE, 256)), dim3(256), 0, stream, rows, cols, vals, cursor, ecv);
  };

  auto splitw = [&](const float* W, u32* o, int K, int N){
    int total = K * N;
    hipLaunchKernelGGL(k_splitw, dim3(cdiv(total, 256)), dim3(256), 0, stream, W, o, K, N, total);
  };
  for(int i = 0; i < 8; i++) splitw(w[i], wtpk[i], HD, HD);
  splitw(m1, m1tpk, HD, HD2);
  splitw(m2, m2tpk, HD2, HD2);
  hipLaunchKernelGGL(k_zero_f, dim3(cdiv(2 * NN, 256)), dim3(256), 0, stream, sc, 2 * NN);
  hipLaunchKernelGGL(k_zero_int, dim3(1), dim3(256), 0, stream, qcnt, 64);

  const int GX = cdiv(NN, 128);       // 782
  const int Ngi = GX * 2;             // mode2 tiles (N=256 -> 2 col-tiles)
  auto mode1 = [&](){
    hipLaunchKernelGGL((k_mfma_gemm<1>), dim3(GX, 2), dim3(256), 0, stream,
                       xpk, m1tpk, b1, (float*)nullptr, h1pk,
                       (const float*)nullptr, (float*)nullptr, NN, HD, HD2);
  };
  auto mode2 = [&](float* score){
    hipLaunchKernelGGL((k_mfma_gemm<2>), dim3(GX, 2), dim3(256), 0, stream,
                       h1pk, m2tpk, b2, (float*)nullptr, (u32*)nullptr,
                       m3, score, NN, HD2, HD2);
  };
  auto gemm0 = [&](int i){
    hipLaunchKernelGGL((k_mfma_gemm<0>), dim3(GX, 1), dim3(256), 0, stream,
                       xpk, wtpk[i], (const float*)nullptr, y, (u32*)nullptr,
                       (const float*)nullptr, (float*)nullptr, NN, HD, HD);
  };

  for(int b = 0; b < 2; b++){
    if(b == 0) build_csr(a1r, a1c, a1v);
    else       build_csr(a2r, a2c, a2v);
    float* score = sc + (size_t)b * NN;
    hipLaunchKernelGGL((k_spmm<true>), dim3(cdiv(NN, 4)), dim3(256), 0, stream,
                       cptr, ecv, w1, xpk);
    if(fused_tier){
      for(int i = 0; i < 8; i++){
        mode1();
        gemm0(i);
        int* qa = qcnt + (b * 8 + i) * 2;
        hipLaunchKernelGGL(k_fused, dim3(1024), dim3(256), 0, stream,
                           h1pk, m2tpk, b2, m3, score, NN, Ngi,
                           cptr, ecv, y, xpk, (i < 7) ? 1 : 0, qa, qa + 1);
      }
      mode1();
      mode2(score);
    } else {
      // r6-proven serial order (y aliases h1pk; gemm0 after mode2)
      mode1();
      mode2(score);
      for(int i = 0; i < 8; i++){
        gemm0(i);
        if(i < 7)
          hipLaunchKernelGGL((k_spmm<true>),  dim3(cdiv(NN, 4)), dim3(256), 0, stream,
                             cptr, ecv, y, xpk);
        else
          hipLaunchKernelGGL((k_spmm<false>), dim3(cdiv(NN, 4)), dim3(256), 0, stream,
                             cptr, ecv, y, xpk);
        mode1();
        mode2(score);
      }
    }
  }

  hipLaunchKernelGGL(k_final, dim3(cdiv(NN, 256)), dim3(256), 0, stream, sc, b3, out);
}

// Round 9
// 4712.795 us; speedup vs baseline: 1.3601x; 1.3601x over previous
//
#include <hip/hip_runtime.h>
#include <hip/hip_fp16.h>

#define NN 100000
#define NE 1600000
#define HD 128
#define HD2 256

typedef unsigned int u32;
typedef unsigned short u16;
typedef _Float16 half8 __attribute__((ext_vector_type(8)));
typedef float floatx4 __attribute__((ext_vector_type(4)));

static inline int cdiv(int a, int b){ return (a + b - 1) / b; }

// ---- split-fp16 packing: x ~= h + l * 2^-12, l pre-scaled by 4096 ----
__device__ __forceinline__ u32 split_pack(float v){
  __half h;
  if(fabsf(v) < 6.103515625e-05f) h = __ushort_as_half((u16)0);
  else h = __float2half_rn(v);
  float hf = __half2float(h);
  __half l = __float2half_rn((v - hf) * 4096.0f);
  return (u32)__half_as_ushort(h) | ((u32)__half_as_ushort(l) << 16);
}

// ---------------- utility kernels ----------------
__global__ void k_zero_int(int* __restrict__ p, int n){
  int i = blockIdx.x * 256 + threadIdx.x;
  if(i < n) p[i] = 0;
}

__global__ void k_zero_f(float* __restrict__ p, int n){
  int i = blockIdx.x * 256 + threadIdx.x;
  if(i < n) p[i] = 0.f;
}

// ---------------- batched CSR build (blockIdx.y = adjacency), packed (col,val) ----------------
__global__ void k_hist2(const int* __restrict__ r0, const int* __restrict__ r1,
                        int* __restrict__ cnt){
  int e = blockIdx.x * 256 + threadIdx.x;
  if(e < NE){
    const int* rows = blockIdx.y ? r1 : r0;
    atomicAdd(&cnt[blockIdx.y * NN + rows[e]], 1);
  }
}

__global__ void k_scan1b(const int* __restrict__ cnt, int* __restrict__ p0,
                         int* __restrict__ p1, int* __restrict__ sums, int n){
  __shared__ int sh[256];
  int z = blockIdx.y;
  const int* c = cnt + z * n;
  int* part = z ? p1 : p0;
  int* sm = sums + z * 128;
  int tid = threadIdx.x;
  int base = blockIdx.x * 1024 + tid * 4;
  int v0 = (base + 0 < n) ? c[base + 0] : 0;
  int v1 = (base + 1 < n) ? c[base + 1] : 0;
  int v2 = (base + 2 < n) ? c[base + 2] : 0;
  int v3 = (base + 3 < n) ? c[base + 3] : 0;
  int s = v0 + v1 + v2 + v3;
  sh[tid] = s;
  __syncthreads();
  for(int d = 1; d < 256; d <<= 1){
    int t = (tid >= d) ? sh[tid - d] : 0;
    __syncthreads();
    sh[tid] += t;
    __syncthreads();
  }
  int excl = sh[tid] - s;
  if(tid == 255) sm[blockIdx.x] = sh[255];
  if(base + 0 < n) part[base + 0] = excl;
  if(base + 1 < n) part[base + 1] = excl + v0;
  if(base + 2 < n) part[base + 2] = excl + v0 + v1;
  if(base + 3 < n) part[base + 3] = excl + v0 + v1 + v2;
}

__global__ void k_scan2b(int* __restrict__ sums, int nb){
  __shared__ int sh[128];
  int* s = sums + blockIdx.x * 128;
  int tid = threadIdx.x;
  int v = (tid < nb) ? s[tid] : 0;
  sh[tid] = v;
  __syncthreads();
  for(int d = 1; d < 128; d <<= 1){
    int t = (tid >= d) ? sh[tid - d] : 0;
    __syncthreads();
    sh[tid] += t;
    __syncthreads();
  }
  if(tid < nb) s[tid] = sh[tid] - v;
}

__global__ void k_scan3b(int* __restrict__ r0, int* __restrict__ r1,
                         int* __restrict__ cursor, const int* __restrict__ sums, int n){
  int z = blockIdx.y;
  int* rowptr = z ? r1 : r0;
  int* cur = cursor + z * n;
  int off = sums[z * 128 + blockIdx.x];
  int tid = threadIdx.x;
  int base = blockIdx.x * 1024 + tid * 4;
  #pragma unroll
  for(int j = 0; j < 4; j++){
    int idx = base + j;
    if(idx < n){ int r = rowptr[idx] + off; rowptr[idx] = r; cur[idx] = r; }
  }
  if(blockIdx.x == 0 && tid == 0) rowptr[n] = NE;
}

__global__ void k_scatter2(const int* __restrict__ r0, const int* __restrict__ c0,
                           const float* __restrict__ v0,
                           const int* __restrict__ r1, const int* __restrict__ c1,
                           const float* __restrict__ v1,
                           int* __restrict__ cursor,
                           uint2* __restrict__ e0, uint2* __restrict__ e1){
  int e = blockIdx.x * 256 + threadIdx.x;
  if(e < NE){
    int z = blockIdx.y;
    const int* rows = z ? r1 : r0;
    const int* cols = z ? c1 : c0;
    const float* vals = z ? v1 : v0;
    int* cur = cursor + z * NN;
    uint2* ecv = z ? e1 : e0;
    int r = rows[e];
    int pp = atomicAdd(&cur[r], 1);
    ecv[pp] = make_uint2((u32)cols[e], __float_as_uint(vals[e]));
  }
}

// weight pre-split: W is [K][N] row-major fp32; out is packed [N][K] (transposed)
__global__ void k_splitw(const float* __restrict__ W, u32* __restrict__ out,
                         int K, int N, int total){
  int idx = blockIdx.x * 256 + threadIdx.x;
  if(idx < total){
    int n = idx / K, k = idx - n * K;
    out[idx] = split_pack(W[(size_t)k * N + n]);
  }
}

// ---------------- SpMM: one wave per node; relu (+ optional l2norm); packed-split output ----
template<bool NORM>
__global__ void k_spmm(const int* __restrict__ rowptr, const uint2* __restrict__ ecv,
                       const float* __restrict__ X, u32* __restrict__ outpk){
  int node = (blockIdx.x << 2) + (threadIdx.x >> 6);
  int lane = threadIdx.x & 63;
  if(node >= NN) return;
  int s = rowptr[node], e = rowptr[node + 1];
  float ax = 0.f, ay = 0.f, bx = 0.f, by = 0.f;
  int i = s;
  for(; i + 15 < e; i += 16){
    uint2 ee[16]; float2 xx[16];
    #pragma unroll
    for(int j = 0; j < 16; j++) ee[j] = ecv[i + j];
    #pragma unroll
    for(int j = 0; j < 16; j++) xx[j] = *(const float2*)(X + (size_t)ee[j].x * HD + lane * 2);
    #pragma unroll
    for(int j = 0; j < 16; j += 4){
      ax += __uint_as_float(ee[j].y)   * xx[j].x   + __uint_as_float(ee[j+1].y) * xx[j+1].x;
      ay += __uint_as_float(ee[j].y)   * xx[j].y   + __uint_as_float(ee[j+1].y) * xx[j+1].y;
      bx += __uint_as_float(ee[j+2].y) * xx[j+2].x + __uint_as_float(ee[j+3].y) * xx[j+3].x;
      by += __uint_as_float(ee[j+2].y) * xx[j+2].y + __uint_as_float(ee[j+3].y) * xx[j+3].y;
    }
  }
  for(; i + 3 < e; i += 4){
    uint2 f0 = ecv[i], f1 = ecv[i+1], f2 = ecv[i+2], f3 = ecv[i+3];
    float2 x0 = *(const float2*)(X + (size_t)f0.x * HD + lane * 2);
    float2 x1 = *(const float2*)(X + (size_t)f1.x * HD + lane * 2);
    float2 x2 = *(const float2*)(X + (size_t)f2.x * HD + lane * 2);
    float2 x3 = *(const float2*)(X + (size_t)f3.x * HD + lane * 2);
    ax += __uint_as_float(f0.y) * x0.x + __uint_as_float(f1.y) * x1.x;
    ay += __uint_as_float(f0.y) * x0.y + __uint_as_float(f1.y) * x1.y;
    bx += __uint_as_float(f2.y) * x2.x + __uint_as_float(f3.y) * x3.x;
    by += __uint_as_float(f2.y) * x2.y + __uint_as_float(f3.y) * x3.y;
  }
  for(; i < e; i++){
    uint2 f0 = ecv[i];
    float2 xv = *(const float2*)(X + (size_t)f0.x * HD + lane * 2);
    ax += __uint_as_float(f0.y) * xv.x;
    ay += __uint_as_float(f0.y) * xv.y;
  }
  ax += bx; ay += by;
  ax = fmaxf(ax, 0.f);
  ay = fmaxf(ay, 0.f);
  if(NORM){
    float ss = ax * ax + ay * ay;
    #pragma unroll
    for(int o = 32; o >= 1; o >>= 1) ss += __shfl_xor(ss, o, 64);
    float scale = 1.f / fmaxf(sqrtf(ss), 1e-12f);
    ax *= scale; ay *= scale;
  }
  *(uint2*)(outpk + (size_t)node * HD + lane * 2) = make_uint2(split_pack(ax), split_pack(ay));
}

// ---------------- split-fp16 MFMA GEMM (round-6-proven body) ----------------
// A: packed [M][K]; Bt: packed [N][K] (pre-transposed).
// MODE 0: Yout = A@B (fp32). MODE 1: Hout = pack(relu(A@B+bias)).
// MODE 2: score[m] += sum_n relu(A@B+bias)[m][n]*m3[n].
// MODE 3: fused — blockIdx.y==0: mode0 with Bt0 -> Yout [M][HD];
//                 blockIdx.y in {1,2}: mode1 col-tile with Bt1 -> Hout [M][HD2].
template<int MODE>
__launch_bounds__(256, 2)
__global__ void k_mfma_gemm(const u32* __restrict__ Apk, const u32* __restrict__ Btpk,
                            const u32* __restrict__ Bt1pk,
                            const float* __restrict__ bias, float* __restrict__ Yout,
                            u32* __restrict__ Hout, const float* __restrict__ m3,
                            float* __restrict__ score, int M, int K, int N){
  __shared__ u16 As_h[128 * 40], As_l[128 * 40];
  __shared__ u16 Bs_h[128 * 40], Bs_l[128 * 40];
  const int tid = threadIdx.x;
  const int lane = tid & 63, wid = tid >> 6;
  const int lm = lane & 15, lg = lane >> 4;
  const int mq = (wid & 1) * 64, nq = (wid >> 1) * 64;
  const int m0 = blockIdx.x * 128;
  int n0 = blockIdx.y * 128;
  const u32* Bt = Btpk;
  bool m0path = true;
  if(MODE == 3){
    m0path = (blockIdx.y == 0);
    if(m0path){ n0 = 0; }
    else      { n0 = (blockIdx.y - 1) * 128; Bt = Bt1pk; }
  }

  floatx4 accA[4][4], accB[4][4];
  #pragma unroll
  for(int i = 0; i < 4; i++)
    #pragma unroll
    for(int j = 0; j < 4; j++){
      accA[i][j] = (floatx4){0.f, 0.f, 0.f, 0.f};
      accB[i][j] = (floatx4){0.f, 0.f, 0.f, 0.f};
    }

  for(int k0 = 0; k0 < K; k0 += 32){
    uint4 av[4], bv[4];
    #pragma unroll
    for(int j = 0; j < 4; j++){
      int li = tid + j * 256;
      int row = li >> 3, kc = (li & 7) * 4;
      int ar = m0 + row; if(ar >= M) ar = M - 1;
      av[j] = *(const uint4*)(Apk + (size_t)ar * K + k0 + kc);
      bv[j] = *(const uint4*)(Bt + (size_t)(n0 + row) * K + k0 + kc);
    }
    if(k0) __syncthreads();
    #pragma unroll
    for(int j = 0; j < 4; j++){
      int li = tid + j * 256;
      int row = li >> 3, kc = (li & 7) * 4;
      int base = row * 40 + kc;
      ushort4 h, l;
      h.x = (u16)(av[j].x & 0xffff); l.x = (u16)(av[j].x >> 16);
      h.y = (u16)(av[j].y & 0xffff); l.y = (u16)(av[j].y >> 16);
      h.z = (u16)(av[j].z & 0xffff); l.z = (u16)(av[j].z >> 16);
      h.w = (u16)(av[j].w & 0xffff); l.w = (u16)(av[j].w >> 16);
      *(ushort4*)&As_h[base] = h;
      *(ushort4*)&As_l[base] = l;
      h.x = (u16)(bv[j].x & 0xffff); l.x = (u16)(bv[j].x >> 16);
      h.y = (u16)(bv[j].y & 0xffff); l.y = (u16)(bv[j].y >> 16);
      h.z = (u16)(bv[j].z & 0xffff); l.z = (u16)(bv[j].z >> 16);
      h.w = (u16)(bv[j].w & 0xffff); l.w = (u16)(bv[j].w >> 16);
      *(ushort4*)&Bs_h[base] = h;
      *(ushort4*)&Bs_l[base] = l;
    }
    __syncthreads();

    half8 fa_h[4], fa_l[4], fb_h[4], fb_l[4];
    #pragma unroll
    for(int s = 0; s < 4; s++){
      int ra = (mq + s * 16 + lm) * 40 + lg * 8;
      fa_h[s] = *(const half8*)&As_h[ra];
      fa_l[s] = *(const half8*)&As_l[ra];
      int rb = (nq + s * 16 + lm) * 40 + lg * 8;
      fb_h[s] = *(const half8*)&Bs_h[rb];
      fb_l[s] = *(const half8*)&Bs_l[rb];
    }
    #pragma unroll
    for(int i = 0; i < 4; i++)
      #pragma unroll
      for(int j = 0; j < 4; j++){
        accA[i][j] = __builtin_amdgcn_mfma_f32_16x16x32_f16(fa_h[i], fb_h[j], accA[i][j], 0, 0, 0);
        accB[i][j] = __builtin_amdgcn_mfma_f32_16x16x32_f16(fa_h[i], fb_l[j], accB[i][j], 0, 0, 0);
        accB[i][j] = __builtin_amdgcn_mfma_f32_16x16x32_f16(fa_l[i], fb_h[j], accB[i][j], 0, 0, 0);
      }
  }

  const float inv4096 = 1.f / 4096.f;
  if(MODE == 0 || (MODE == 3 && m0path)){
    int ldy = (MODE == 3) ? HD : N;
    #pragma unroll
    for(int i = 0; i < 4; i++)
      #pragma unroll
      for(int r = 0; r < 4; r++){
        int m = m0 + mq + i * 16 + lg * 4 + r;
        if(m < M){
          #pragma unroll
          for(int j = 0; j < 4; j++){
            int c = n0 + nq + j * 16 + lm;
            Yout[(size_t)m * ldy + c] = accA[i][j][r] + accB[i][j][r] * inv4096;
          }
        }
      }
  } else if(MODE == 1 || MODE == 3){
    int ldh = (MODE == 3) ? HD2 : N;
    #pragma unroll
    for(int i = 0; i < 4; i++)
      #pragma unroll
      for(int r = 0; r < 4; r++){
        int m = m0 + mq + i * 16 + lg * 4 + r;
        if(m < M){
          #pragma unroll
          for(int j = 0; j < 4; j++){
            int c = n0 + nq + j * 16 + lm;
            float v = fmaxf(accA[i][j][r] + accB[i][j][r] * inv4096 + bias[c], 0.f);
            Hout[(size_t)m * ldh + c] = split_pack(v);
          }
        }
      }
  } else {
    #pragma unroll
    for(int i = 0; i < 4; i++)
      #pragma unroll
      for(int r = 0; r < 4; r++){
        float s = 0.f;
        #pragma unroll
        for(int j = 0; j < 4; j++){
          int c = n0 + nq + j * 16 + lm;
          float v = fmaxf(accA[i][j][r] + accB[i][j][r] * inv4096 + bias[c], 0.f);
          s = fmaf(v, m3[c], s);
        }
        s += __shfl_xor(s, 1, 64);
        s += __shfl_xor(s, 2, 64);
        s += __shfl_xor(s, 4, 64);
        s += __shfl_xor(s, 8, 64);
        int m = m0 + mq + i * 16 + lg * 4 + r;
        if(lm == 0 && m < M) atomicAdd(&score[m], s);
      }
  }
}

__global__ void k_final(const float* __restrict__ sc, const float* __restrict__ b3,
                        float* __restrict__ out){
  int i = blockIdx.x * 256 + threadIdx.x;
  if(i < NN){
    float b = 9.f * b3[0];
    out[i] = (sc[i] + b) * (sc[NN + i] + b);
  }
}

// ---------------- launcher ----------------
extern "C" void kernel_launch(void* const* d_in, const int* in_sizes, int n_in,
                              void* d_out, int out_size, void* d_ws, size_t ws_size,
                              hipStream_t stream){
  const int*   a1r = (const int*)d_in[0];
  const int*   a1c = (const int*)d_in[1];
  const float* a1v = (const float*)d_in[2];
  const int*   a2r = (const int*)d_in[3];
  const int*   a2c = (const int*)d_in[4];
  const float* a2v = (const float*)d_in[5];
  const float* w1  = (const float*)d_in[6];
  const float* w[8];
  for(int i = 0; i < 8; i++) w[i] = (const float*)d_in[7 + i];
  const float* m1 = (const float*)d_in[15];
  const float* b1 = (const float*)d_in[16];
  const float* m2 = (const float*)d_in[17];
  const float* b2 = (const float*)d_in[18];
  const float* m3 = (const float*)d_in[19];
  const float* b3 = (const float*)d_in[20];
  float* out = (float*)d_out;

  char* base = (char*)d_ws;
  size_t off = 0;
  auto alloc = [&](size_t bytes) -> char* {
    char* r = base + off;
    off += (bytes + 255) & ~(size_t)255;
    return r;
  };
  int*   c1ptr = (int*)  alloc((size_t)(NN + 1) * 4);
  int*   c2ptr = (int*)  alloc((size_t)(NN + 1) * 4);
  uint2* ecv1  = (uint2*)alloc((size_t)NE * 8);
  uint2* ecv2  = (uint2*)alloc((size_t)NE * 8);
  int*   cursor= (int*)  alloc((size_t)2 * NN * 4);
  int*   sums  = (int*)  alloc(1024);
  float* sc    = (float*)alloc((size_t)2 * NN * 4);
  u32*   wtpk[8];
  for(int i = 0; i < 8; i++) wtpk[i] = (u32*)alloc((size_t)HD * HD * 4);
  u32*   m1tpk = (u32*)alloc((size_t)HD2 * HD * 4);
  u32*   m2tpk = (u32*)alloc((size_t)HD2 * HD2 * 4);
  u32*   xpk   = (u32*)alloc((size_t)NN * HD * 4);
  u32*   h1pk  = (u32*)alloc((size_t)NN * HD2 * 4);
  // fused01 tier needs dedicated y (fp32 [NN][HD]); else alias h1pk and run r6 schedule
  size_t need_ded = off + (((size_t)NN * HD * 4 + 255) & ~(size_t)255);
  bool ded_y = (ws_size >= need_ded);
  float* y = ded_y ? (float*)alloc((size_t)NN * HD * 4) : (float*)h1pk;

  // ---- batched CSR build (both adjacencies) ----
  hipLaunchKernelGGL(k_zero_int, dim3(cdiv(2 * NN, 256)), dim3(256), 0, stream, cursor, 2 * NN);
  hipLaunchKernelGGL(k_hist2, dim3(cdiv(NE, 256), 2), dim3(256), 0, stream, a1r, a2r, cursor);
  const int SCAN_BLOCKS = cdiv(NN, 1024);
  hipLaunchKernelGGL(k_scan1b, dim3(SCAN_BLOCKS, 2), dim3(256), 0, stream, cursor, c1ptr, c2ptr, sums, NN);
  hipLaunchKernelGGL(k_scan2b, dim3(2), dim3(128), 0, stream, sums, SCAN_BLOCKS);
  hipLaunchKernelGGL(k_scan3b, dim3(SCAN_BLOCKS, 2), dim3(256), 0, stream, c1ptr, c2ptr, cursor, sums, NN);
  hipLaunchKernelGGL(k_scatter2, dim3(cdiv(NE, 256), 2), dim3(256), 0, stream,
                     a1r, a1c, a1v, a2r, a2c, a2v, cursor, ecv1, ecv2);

  auto splitw = [&](const float* W, u32* o, int K, int N){
    int total = K * N;
    hipLaunchKernelGGL(k_splitw, dim3(cdiv(total, 256)), dim3(256), 0, stream, W, o, K, N, total);
  };
  for(int i = 0; i < 8; i++) splitw(w[i], wtpk[i], HD, HD);
  splitw(m1, m1tpk, HD, HD2);
  splitw(m2, m2tpk, HD2, HD2);
  hipLaunchKernelGGL(k_zero_f, dim3(cdiv(2 * NN, 256)), dim3(256), 0, stream, sc, 2 * NN);

  const int GX = cdiv(NN, 128);   // 782
  auto mode1 = [&](){
    hipLaunchKernelGGL((k_mfma_gemm<1>), dim3(GX, 2), dim3(256), 0, stream,
                       xpk, m1tpk, (const u32*)nullptr, b1, (float*)nullptr, h1pk,
                       (const float*)nullptr, (float*)nullptr, NN, HD, HD2);
  };
  auto mode2 = [&](float* score){
    hipLaunchKernelGGL((k_mfma_gemm<2>), dim3(GX, 2), dim3(256), 0, stream,
                       h1pk, m2tpk, (const u32*)nullptr, b2, (float*)nullptr, (u32*)nullptr,
                       m3, score, NN, HD2, HD2);
  };
  auto gemm0 = [&](int i){
    hipLaunchKernelGGL((k_mfma_gemm<0>), dim3(GX, 1), dim3(256), 0, stream,
                       xpk, wtpk[i], (const u32*)nullptr, (const float*)nullptr, y, (u32*)nullptr,
                       (const float*)nullptr, (float*)nullptr, NN, HD, HD);
  };
  auto fused01 = [&](int i){
    hipLaunchKernelGGL((k_mfma_gemm<3>), dim3(GX, 3), dim3(256), 0, stream,
                       xpk, wtpk[i], m1tpk, b1, y, h1pk,
                       (const float*)nullptr, (float*)nullptr, NN, HD, 0);
  };

  for(int b = 0; b < 2; b++){
    const int* rp = b ? c2ptr : c1ptr;
    const uint2* ecv = b ? ecv2 : ecv1;
    float* score = sc + (size_t)b * NN;
    hipLaunchKernelGGL((k_spmm<true>), dim3(cdiv(NN, 4)), dim3(256), 0, stream,
                       rp, ecv, w1, xpk);
    if(ded_y){
      // spmm; 8x [fused01(h1,y); mode2; spmm]; mode1; mode2
      for(int i = 0; i < 8; i++){
        fused01(i);
        mode2(score);
        if(i < 7)
          hipLaunchKernelGGL((k_spmm<true>),  dim3(cdiv(NN, 4)), dim3(256), 0, stream,
                             rp, ecv, y, xpk);
        else
          hipLaunchKernelGGL((k_spmm<false>), dim3(cdiv(NN, 4)), dim3(256), 0, stream,
                             rp, ecv, y, xpk);
      }
      mode1();
      mode2(score);
    } else {
      // r6-proven serial order (y aliases h1pk)
      mode1();
      mode2(score);
      for(int i = 0; i < 8; i++){
        gemm0(i);
        if(i < 7)
          hipLaunchKernelGGL((k_spmm<true>),  dim3(cdiv(NN, 4)), dim3(256), 0, stream,
                             rp, ecv, y, xpk);
        else
          hipLaunchKernelGGL((k_spmm<false>), dim3(cdiv(NN, 4)), dim3(256), 0, stream,
                             rp, ecv, y, xpk);
        mode1();
        mode2(score);
      }
    }
  }

  hipLaunchKernelGGL(k_final, dim3(cdiv(NN, 256)), dim3(256), 0, stream, sc, b3, out);
}